// Round 14
// baseline (550.639 us; speedup 1.0000x reference)
//
#include <hip/hip_runtime.h>

#define F_IN 512
#define F_HID 16
#define F_OUT 7
#define BUCKET 128          // nodes per bucket
#define LB 7                // log2(BUCKET)
#define CHUNK 4096          // edges per partition block
#define MAXNB 1024          // max buckets supported by block-local scans
#define BSTR 8192           // bedges fixed bucket stride (mean 4092, sigma 64 -> 64-sigma safe)
#define BSTR2 8704          // bedges2 fixed stride (8-pad worst case ~5300 < 8704)

// GEMM1 (wave-split-K, full K): 8 lanes per row, W in LDS
#define WSTR 9              // LDS W row stride in float2 (9 -> 8 kl-lanes hit 8 bank-pairs)

typedef int   int4v   __attribute__((ext_vector_type(4)));
typedef float float2v __attribute__((ext_vector_type(2)));
typedef float float4v __attribute__((ext_vector_type(4)));
typedef unsigned int uint4v __attribute__((ext_vector_type(4)));

static __device__ __forceinline__ unsigned short f2bf(float f) {   // RNE
    unsigned int u = __float_as_uint(f);
    u += 0x7FFFu + ((u >> 16) & 1u);
    return (unsigned short)(u >> 16);
}
static __device__ __forceinline__ float bf2f(unsigned short s) {
    return __uint_as_float((unsigned int)s << 16);
}

// ---- init: cursors, per-node degree zeroing, sentinel rows of h1b/h2b ----
__global__ void k_init(int* __restrict__ cursor, int* __restrict__ deg,
                       unsigned int* __restrict__ h1u, unsigned int* __restrict__ h2u,
                       int NB, int npad, int n) {
    int i = blockIdx.x * 256 + threadIdx.x;
    if (i < NB) cursor[i] = i * BSTR;
    if (i < npad) deg[i] = 0;
    if (blockIdx.x == 0) {
        if (threadIdx.x < 8) h1u[(size_t)n * 8 + threadIdx.x] = 0u;
        if (threadIdx.x < 4) h2u[(size_t)n * 4 + threadIdx.x] = 0u;
    }
}

// ------- place: block rank-and-reorder + global per-node degree atomics -------
__global__ __launch_bounds__(256) void k_place4(
        const int* __restrict__ src, const int* __restrict__ dst,
        int* __restrict__ cursor, int* __restrict__ deg,
        int* __restrict__ bedges, int E, int NB) {
    __shared__ int h[MAXNB];                   // hist -> exclusive rank cursor
    __shared__ int s[MAXNB];                   // inclusive scan -> dbase
    __shared__ int sedge[CHUNK];               // 16 KB reordered packed edges
    __shared__ unsigned short sbkt[CHUNK];     // 8 KB bucket id per slot
    int t = threadIdx.x, blk = blockIdx.x;
    for (int i = t; i < MAXNB; i += 256) h[i] = 0;
    __syncthreads();
    int base = blk * CHUNK;
    int4v d4[4], s4[4];
#pragma unroll
    for (int it = 0; it < 4; ++it) {
        int e = base + (it * 256 + t) * 4;
        if (e < E) {                           // E % 4 == 0 -> whole quad valid
            d4[it] = __builtin_nontemporal_load((const int4v*)(dst + e));
            s4[it] = __builtin_nontemporal_load((const int4v*)(src + e));
        } else {
            int sent = NB << LB;               // sentinel bucket NB (skipped at write-out)
            d4[it].x = sent; d4[it].y = sent; d4[it].z = sent; d4[it].w = sent;
            s4[it].x = 0;    s4[it].y = 0;    s4[it].z = 0;    s4[it].w = 0;
        }
        atomicAdd(&h[d4[it].x >> LB], 1);
        atomicAdd(&h[d4[it].y >> LB], 1);
        atomicAdd(&h[d4[it].z >> LB], 1);
        atomicAdd(&h[d4[it].w >> LB], 1);
        // per-node degree (replaces psort pass 1); sentinel hits deg[NB*BUCKET] pad
        atomicAdd(&deg[d4[it].x], 1);
        atomicAdd(&deg[d4[it].y], 1);
        atomicAdd(&deg[d4[it].z], 1);
        atomicAdd(&deg[d4[it].w], 1);
    }
    __syncthreads();
    for (int i = t; i < MAXNB; i += 256) s[i] = h[i];
    __syncthreads();
    // inclusive Hillis-Steele scan of s[0..1023], 256 threads x 4
    for (int off = 1; off < MAXNB; off <<= 1) {
        int v[4];
#pragma unroll
        for (int j = 0; j < 4; ++j) {
            int i = t + j * 256;
            v[j] = s[i] + ((i >= off) ? s[i - off] : 0);
        }
        __syncthreads();
#pragma unroll
        for (int j = 0; j < 4; ++j) s[t + j * 256] = v[j];
        __syncthreads();
    }
    // h := exclusive rank base; s := dbase = (atomic run reservation) - local_excl
    for (int i = t; i < MAXNB; i += 256) {
        int incl = s[i], cnt = h[i];
        int excl = incl - cnt;
        h[i] = excl;
        int db = 0;
        if (i < NB && cnt > 0)
            db = atomicAdd(&cursor[i], cnt) - excl;    // device-scope global atomic
        s[i] = db;
    }
    __syncthreads();
    // rank & reorder into LDS
#pragma unroll
    for (int it = 0; it < 4; ++it) {
        int d, sv, b, p;
        d = d4[it].x; sv = s4[it].x; b = d >> LB; p = atomicAdd(&h[b], 1);
        sedge[p] = (sv << 8) | (d & (BUCKET - 1)); sbkt[p] = (unsigned short)b;
        d = d4[it].y; sv = s4[it].y; b = d >> LB; p = atomicAdd(&h[b], 1);
        sedge[p] = (sv << 8) | (d & (BUCKET - 1)); sbkt[p] = (unsigned short)b;
        d = d4[it].z; sv = s4[it].z; b = d >> LB; p = atomicAdd(&h[b], 1);
        sedge[p] = (sv << 8) | (d & (BUCKET - 1)); sbkt[p] = (unsigned short)b;
        d = d4[it].w; sv = s4[it].w; b = d >> LB; p = atomicAdd(&h[b], 1);
        sedge[p] = (sv << 8) | (d & (BUCKET - 1)); sbkt[p] = (unsigned short)b;
    }
    __syncthreads();
    // write-out: consecutive j in a bucket run -> consecutive dest (coalesced bursts)
    for (int j = t; j < CHUNK; j += 256) {
        int b = sbkt[j];
        if (b < NB)
            __builtin_nontemporal_store(sedge[j], bedges + s[b] + j);
    }
}

// ---- psort: counts from deg[] (pass 1 deleted); 8-padded runs; coalesced write ----
__global__ __launch_bounds__(256) void k_psort(
        const int* __restrict__ cursor, const int* __restrict__ deg,
        const int* __restrict__ bedges, int* __restrict__ bedges2,
        float* __restrict__ dinv, int* __restrict__ node_off,
        int* __restrict__ node_nq, int n) {
    __shared__ int sc[BUCKET];                 // padded inclusive scan
    __shared__ int cur[BUCKET];
    __shared__ int sedge[BSTR2];               // 34 KB ranked srcs
    int b = blockIdx.x, t = threadIdx.x;
    int base = b * BSTR;
    int ne = cursor[b] - base;
    int cnt = 0, p = 0;
    if (t < BUCKET) {
        cnt = deg[b * BUCKET + t];             // from place4's global atomics
        p = (cnt + 7) & ~7;                    // 8-edge pad (2 quads -> agg ILP 8)
        sc[t] = p;
    }
    __syncthreads();
    for (int off = 1; off < BUCKET; off <<= 1) {
        int v = 0;
        if (t < BUCKET) { v = sc[t]; if (t >= off) v += sc[t - off]; }
        __syncthreads();
        if (t < BUCKET) sc[t] = v;
        __syncthreads();
    }
    if (t < BUCKET) {
        int w = sc[t] - p;
        cur[t] = w;
        int node = b * BUCKET + t;
        if (node < n) {
            dinv[node] = rsqrtf((float)(cnt + 1));      // +1 self-loop
            node_off[node] = b * BSTR2 + w;
            node_nq[node] = p >> 3;                     // #8-edge groups
        }
    }
    __syncthreads();
    // single pass: rank into LDS
    int nq = ne >> 2, tail = ne & 3;
    for (int q = t; q < nq; q += 256) {
        int4v v = *(const int4v*)(bedges + base + (q << 2));
        int pos;
        pos = atomicAdd(&cur[v.x & 127], 1); sedge[pos] = v.x >> 8;
        pos = atomicAdd(&cur[v.y & 127], 1); sedge[pos] = v.y >> 8;
        pos = atomicAdd(&cur[v.z & 127], 1); sedge[pos] = v.z >> 8;
        pos = atomicAdd(&cur[v.w & 127], 1); sedge[pos] = v.w >> 8;
    }
    if (t < tail) {
        int v = bedges[base + (nq << 2) + t];
        int pos = atomicAdd(&cur[v & 127], 1); sedge[pos] = v >> 8;
    }
    __syncthreads();
    if (t < BUCKET) {
        int endc = cur[t];
        for (int i = endc; i < sc[t]; ++i) sedge[i] = n;   // sentinel -> zero row
    }
    __syncthreads();
    int total = sc[BUCKET - 1];                // multiple of 8
    int* dst2 = bedges2 + b * BSTR2;           // 16B-aligned (BSTR2*4 % 16 == 0)
    for (int j4 = t; j4 < (total >> 2); j4 += 256) {
        int4v v = *(const int4v*)(sedge + (j4 << 2));
        __builtin_nontemporal_store(v, (int4v*)(dst2 + (j4 << 2)));
    }
}

// ---- GEMM1 (wave-split-K, FULL K=512): 8 lanes/row, writes bf16 h1b directly ----
__global__ __launch_bounds__(256) void k_gemm1wf(
        const float* __restrict__ x, const float* __restrict__ W,
        const float* __restrict__ dinv, unsigned int* __restrict__ h1u, int n) {
    __shared__ float2v Ws[512 * WSTR];         // 36864 B -> 4 blocks/CU
    int t = threadIdx.x;

    // stage full W: 4096 float2 -> Ws[k*WSTR + c2]
    const float2v* Wg = (const float2v*)W;
#pragma unroll
    for (int it = 0; it < 16; ++it) {
        int m = it * 256 + t;                  // m in [0,4096)
        Ws[(m >> 3) * WSTR + (m & 7)] = Wg[m];
    }
    __syncthreads();

    int r  = blockIdx.x * 32 + (t >> 3);       // 32 rows/block, 8 lanes/row
    int kl = t & 7;                            // K sub-lane
    if (r >= n) return;
    const float* xr = x + (size_t)r * F_IN + kl * 4;
    float4v v[16];
#pragma unroll
    for (int i = 0; i < 16; ++i)
        v[i] = *(const float4v*)(xr + i * 32);

    float2v acc2[8];
#pragma unroll
    for (int c2 = 0; c2 < 8; ++c2) acc2[c2] = (float2v){0.0f, 0.0f};

#pragma unroll
    for (int i = 0; i < 16; ++i) {
        int kb = i * 32 + kl * 4;
#pragma unroll
        for (int j = 0; j < 4; ++j) {
            float xv = v[i][j];
            const float2v* wr = Ws + (kb + j) * WSTR;
#pragma unroll
            for (int c2 = 0; c2 < 8; ++c2)
                acc2[c2] += xv * wr[c2];
        }
    }
    // reduce over the 8 K-lanes (xor masks 1,2,4 stay within the row group)
#pragma unroll
    for (int m = 1; m <= 4; m <<= 1) {
#pragma unroll
        for (int c2 = 0; c2 < 8; ++c2) {
            acc2[c2].x += __shfl_xor(acc2[c2].x, m);
            acc2[c2].y += __shfl_xor(acc2[c2].y, m);
        }
    }
    float dv = dinv[r];
    unsigned int u = (unsigned int)f2bf(dv * acc2[kl].x)
                   | ((unsigned int)f2bf(dv * acc2[kl].y) << 16);
    h1u[(size_t)r * 8 + kl] = u;               // lane kl owns cols {2kl, 2kl+1}
}

// ---- agg layer 1 + relu/bias + GEMM2 fused: 8 lanes/node, 2 quads/iter (ILP 8) ----
__global__ __launch_bounds__(1024) void k_aggF1(
        const int* __restrict__ node_off, const int* __restrict__ node_nq,
        const int* __restrict__ bedges2, const unsigned int* __restrict__ h1u,
        const float* __restrict__ dinv, const float* __restrict__ b1,
        const float* __restrict__ W2, unsigned short* __restrict__ h2b, int n) {
    int tg = blockIdx.x * 1024 + threadIdx.x;
    int node = tg >> 3, c = tg & 7;            // lane owns cols {2c, 2c+1}
    if (node >= n) return;
    int off = node_off[node], nq = node_nq[node];
    unsigned int su = h1u[(size_t)node * 8 + c];        // self-loop (pre-scaled)
    float ax = bf2f((unsigned short)su);
    float ay = bf2f((unsigned short)(su >> 16));
    for (int q = 0; q < nq; ++q) {             // nq = #8-edge groups
        const int4v* bp = (const int4v*)(bedges2 + off + (q << 3));
        int4v s0 = bp[0], s1 = bp[1];
        unsigned int u0 = h1u[(size_t)s0.x * 8 + c];
        unsigned int u1 = h1u[(size_t)s0.y * 8 + c];
        unsigned int u2 = h1u[(size_t)s0.z * 8 + c];
        unsigned int u3 = h1u[(size_t)s0.w * 8 + c];
        unsigned int u4 = h1u[(size_t)s1.x * 8 + c];
        unsigned int u5 = h1u[(size_t)s1.y * 8 + c];
        unsigned int u6 = h1u[(size_t)s1.z * 8 + c];
        unsigned int u7 = h1u[(size_t)s1.w * 8 + c];
        ax += bf2f((unsigned short)u0) + bf2f((unsigned short)u1)
            + bf2f((unsigned short)u2) + bf2f((unsigned short)u3)
            + bf2f((unsigned short)u4) + bf2f((unsigned short)u5)
            + bf2f((unsigned short)u6) + bf2f((unsigned short)u7);
        ay += bf2f((unsigned short)(u0 >> 16)) + bf2f((unsigned short)(u1 >> 16))
            + bf2f((unsigned short)(u2 >> 16)) + bf2f((unsigned short)(u3 >> 16))
            + bf2f((unsigned short)(u4 >> 16)) + bf2f((unsigned short)(u5 >> 16))
            + bf2f((unsigned short)(u6 >> 16)) + bf2f((unsigned short)(u7 >> 16));
    }
    float dv = dinv[node];
    float zx = fmaxf(dv * ax + b1[2 * c], 0.0f);
    float zy = fmaxf(dv * ay + b1[2 * c + 1], 0.0f);
    float h[F_OUT];
#pragma unroll
    for (int o = 0; o < F_OUT; ++o)
        h[o] = zx * W2[(2 * c) * F_OUT + o] + zy * W2[(2 * c + 1) * F_OUT + o];
#pragma unroll
    for (int sft = 4; sft >= 1; sft >>= 1)
#pragma unroll
        for (int o = 0; o < F_OUT; ++o) h[o] += __shfl_xor(h[o], sft, 8);
    unsigned short w = (c < F_OUT) ? f2bf(dv * h[c]) : (unsigned short)0;
    h2b[((size_t)node << 3) + c] = w;
}

// ------ agg layer 2 + bias fused: 4 lanes/node, 2 quads/iter (ILP 8) ------
__global__ __launch_bounds__(1024) void k_aggF2(
        const int* __restrict__ node_off, const int* __restrict__ node_nq,
        const int* __restrict__ bedges2, const unsigned int* __restrict__ h2u,
        const float* __restrict__ dinv, const float* __restrict__ b2,
        float* __restrict__ out, int n) {
    int tg = blockIdx.x * 1024 + threadIdx.x;
    int node = tg >> 2, c = tg & 3;            // lane owns cols {2c, 2c+1}
    if (node >= n) return;
    int off = node_off[node], nq = node_nq[node];
    unsigned int su = h2u[(size_t)node * 4 + c];        // self-loop (col7 = 0)
    float ax = bf2f((unsigned short)su);
    float ay = bf2f((unsigned short)(su >> 16));
    for (int q = 0; q < nq; ++q) {             // nq = #8-edge groups
        const int4v* bp = (const int4v*)(bedges2 + off + (q << 3));
        int4v s0 = bp[0], s1 = bp[1];
        unsigned int u0 = h2u[(size_t)s0.x * 4 + c];
        unsigned int u1 = h2u[(size_t)s0.y * 4 + c];
        unsigned int u2 = h2u[(size_t)s0.z * 4 + c];
        unsigned int u3 = h2u[(size_t)s0.w * 4 + c];
        unsigned int u4 = h2u[(size_t)s1.x * 4 + c];
        unsigned int u5 = h2u[(size_t)s1.y * 4 + c];
        unsigned int u6 = h2u[(size_t)s1.z * 4 + c];
        unsigned int u7 = h2u[(size_t)s1.w * 4 + c];
        ax += bf2f((unsigned short)u0) + bf2f((unsigned short)u1)
            + bf2f((unsigned short)u2) + bf2f((unsigned short)u3)
            + bf2f((unsigned short)u4) + bf2f((unsigned short)u5)
            + bf2f((unsigned short)u6) + bf2f((unsigned short)u7);
        ay += bf2f((unsigned short)(u0 >> 16)) + bf2f((unsigned short)(u1 >> 16))
            + bf2f((unsigned short)(u2 >> 16)) + bf2f((unsigned short)(u3 >> 16))
            + bf2f((unsigned short)(u4 >> 16)) + bf2f((unsigned short)(u5 >> 16))
            + bf2f((unsigned short)(u6 >> 16)) + bf2f((unsigned short)(u7 >> 16));
    }
    float dv = dinv[node];
    out[(size_t)node * F_OUT + 2 * c] = dv * ax + b2[2 * c];
    if (2 * c + 1 < F_OUT)
        out[(size_t)node * F_OUT + 2 * c + 1] = dv * ay + b2[2 * c + 1];
}

extern "C" void kernel_launch(void* const* d_in, const int* in_sizes, int n_in,
                              void* d_out, int out_size, void* d_ws, size_t ws_size,
                              hipStream_t stream) {
    const float* x  = (const float*)d_in[0];
    const int*   ei = (const int*)d_in[1];      // int64 in source but JAX x64 off -> int32
    const float* W1 = (const float*)d_in[2];
    const float* b1 = (const float*)d_in[3];
    const float* W2 = (const float*)d_in[4];
    const float* b2 = (const float*)d_in[5];
    float* out = (float*)d_out;

    const int n = in_sizes[0] / F_IN;       // 100000
    const int E = in_sizes[1] / 2;          // 3200000
    const int* src = ei;
    const int* dst = ei + E;

    const int NB = (n + BUCKET - 1) / BUCKET;   // 782 (sentinel bucket NB fits < MAXNB)
    const int PBLK = (E + CHUNK - 1) / CHUNK;   // 782
    const int NRB = (n + 31) / 32;              // 3125 row-blocks for gemm1wf
    const int npad = (NB + 1) * BUCKET;         // deg[] size incl. sentinel bucket

    // workspace layout (16B-aligned sections)
    size_t Np = ((size_t)n + 3) & ~(size_t)3;
    char* ws = (char*)d_ws;
    int*   cursor       = (int*)ws;             ws += MAXNB * 4;
    int*   deg          = (int*)ws;             ws += (size_t)npad * 4;         // 400 KB
    float* dinv         = (float*)ws;           ws += Np * 4;
    int*   node_off     = (int*)ws;             ws += Np * 4;
    int*   node_nq      = (int*)ws;             ws += Np * 4;
    int*   bedges       = (int*)ws;             ws += (size_t)NB * BSTR * 4;    // 25.6 MB
    int*   bedges2      = (int*)ws;             ws += (size_t)NB * BSTR2 * 4;   // 27.2 MB
    unsigned short* h1b = (unsigned short*)ws;  ws += (Np + 4) * F_HID * 2;     // 3.2 MB
    unsigned short* h2b = (unsigned short*)ws;  ws += (Np + 4) * 8 * 2;         // 1.6 MB
    unsigned int* h1u = (unsigned int*)h1b;
    unsigned int* h2u = (unsigned int*)h2b;

    k_init    <<<(npad + 255) / 256, 256, 0, stream>>>(cursor, deg, h1u, h2u, NB, npad, n);
    k_place4  <<<PBLK, 256, 0, stream>>>(src, dst, cursor, deg, bedges, E, NB);
    k_psort   <<<NB, 256, 0, stream>>>(cursor, deg, bedges, bedges2, dinv, node_off, node_nq, n);
    k_gemm1wf <<<NRB, 256, 0, stream>>>(x, W1, dinv, h1u, n);
    k_aggF1   <<<((size_t)n * 8 + 1023) / 1024, 1024, 0, stream>>>(node_off, node_nq, bedges2, h1u, dinv, b1, W2, h2b, n);
    k_aggF2   <<<((size_t)n * 4 + 1023) / 1024, 1024, 0, stream>>>(node_off, node_nq, bedges2, h2u, dinv, b2, out, n);
}

// Round 15
// 420.505 us; speedup vs baseline: 1.3095x; 1.3095x over previous
//
#include <hip/hip_runtime.h>

#define F_IN 512
#define F_HID 16
#define F_OUT 7
#define BUCKET 128          // nodes per bucket
#define LB 7                // log2(BUCKET)
#define CHUNK 4096          // edges per partition block
#define MAXNB 1024          // max buckets supported by block-local scans
#define BSTR 8192           // bedges fixed bucket stride (mean 4092, sigma 64 -> 64-sigma safe)
#define BSTR2 8704          // bedges2 fixed stride (8-pad worst case ~5300 < 8704)

// GEMM1 (wave-split-K, full K): 8 lanes per row, W in LDS
#define WSTR 9              // LDS W row stride in float2 (9 -> 8 kl-lanes hit 8 bank-pairs)

typedef int   int4v   __attribute__((ext_vector_type(4)));
typedef float float2v __attribute__((ext_vector_type(2)));
typedef float float4v __attribute__((ext_vector_type(4)));
typedef unsigned int uint4v __attribute__((ext_vector_type(4)));

static __device__ __forceinline__ unsigned short f2bf(float f) {   // RNE
    unsigned int u = __float_as_uint(f);
    u += 0x7FFFu + ((u >> 16) & 1u);
    return (unsigned short)(u >> 16);
}
static __device__ __forceinline__ float bf2f(unsigned short s) {
    return __uint_as_float((unsigned int)s << 16);
}

// ---- init: fixed-stride bucket cursors + zero sentinel rows of h1b/h2b ----
__global__ void k_init(int* __restrict__ cursor, unsigned int* __restrict__ h1u,
                       unsigned int* __restrict__ h2u, int NB, int n) {
    int i = blockIdx.x * 256 + threadIdx.x;
    if (i < NB) cursor[i] = i * BSTR;
    if (blockIdx.x == 0) {
        if (threadIdx.x < 8) h1u[(size_t)n * 8 + threadIdx.x] = 0u;
        if (threadIdx.x < 4) h2u[(size_t)n * 4 + threadIdx.x] = 0u;
    }
}

// ------- place: block rank-and-reorder (r13 version -- NO global deg atomics) -------
__global__ __launch_bounds__(256) void k_place4(
        const int* __restrict__ src, const int* __restrict__ dst,
        int* __restrict__ cursor, int* __restrict__ bedges, int E, int NB) {
    __shared__ int h[MAXNB];                   // hist -> exclusive rank cursor
    __shared__ int s[MAXNB];                   // inclusive scan -> dbase
    __shared__ int sedge[CHUNK];               // 16 KB reordered packed edges
    __shared__ unsigned short sbkt[CHUNK];     // 8 KB bucket id per slot
    int t = threadIdx.x, blk = blockIdx.x;
    for (int i = t; i < MAXNB; i += 256) h[i] = 0;
    __syncthreads();
    int base = blk * CHUNK;
    int4v d4[4], s4[4];
#pragma unroll
    for (int it = 0; it < 4; ++it) {
        int e = base + (it * 256 + t) * 4;
        if (e < E) {                           // E % 4 == 0 -> whole quad valid
            d4[it] = __builtin_nontemporal_load((const int4v*)(dst + e));
            s4[it] = __builtin_nontemporal_load((const int4v*)(src + e));
        } else {
            int sent = NB << LB;               // sentinel bucket NB (skipped at write-out)
            d4[it].x = sent; d4[it].y = sent; d4[it].z = sent; d4[it].w = sent;
            s4[it].x = 0;    s4[it].y = 0;    s4[it].z = 0;    s4[it].w = 0;
        }
        atomicAdd(&h[d4[it].x >> LB], 1);
        atomicAdd(&h[d4[it].y >> LB], 1);
        atomicAdd(&h[d4[it].z >> LB], 1);
        atomicAdd(&h[d4[it].w >> LB], 1);
    }
    __syncthreads();
    for (int i = t; i < MAXNB; i += 256) s[i] = h[i];
    __syncthreads();
    // inclusive Hillis-Steele scan of s[0..1023], 256 threads x 4
    for (int off = 1; off < MAXNB; off <<= 1) {
        int v[4];
#pragma unroll
        for (int j = 0; j < 4; ++j) {
            int i = t + j * 256;
            v[j] = s[i] + ((i >= off) ? s[i - off] : 0);
        }
        __syncthreads();
#pragma unroll
        for (int j = 0; j < 4; ++j) s[t + j * 256] = v[j];
        __syncthreads();
    }
    // h := exclusive rank base; s := dbase = (atomic run reservation) - local_excl
    for (int i = t; i < MAXNB; i += 256) {
        int incl = s[i], cnt = h[i];
        int excl = incl - cnt;
        h[i] = excl;
        int db = 0;
        if (i < NB && cnt > 0)
            db = atomicAdd(&cursor[i], cnt) - excl;    // device-scope global atomic
        s[i] = db;
    }
    __syncthreads();
    // rank & reorder into LDS
#pragma unroll
    for (int it = 0; it < 4; ++it) {
        int d, sv, b, p;
        d = d4[it].x; sv = s4[it].x; b = d >> LB; p = atomicAdd(&h[b], 1);
        sedge[p] = (sv << 8) | (d & (BUCKET - 1)); sbkt[p] = (unsigned short)b;
        d = d4[it].y; sv = s4[it].y; b = d >> LB; p = atomicAdd(&h[b], 1);
        sedge[p] = (sv << 8) | (d & (BUCKET - 1)); sbkt[p] = (unsigned short)b;
        d = d4[it].z; sv = s4[it].z; b = d >> LB; p = atomicAdd(&h[b], 1);
        sedge[p] = (sv << 8) | (d & (BUCKET - 1)); sbkt[p] = (unsigned short)b;
        d = d4[it].w; sv = s4[it].w; b = d >> LB; p = atomicAdd(&h[b], 1);
        sedge[p] = (sv << 8) | (d & (BUCKET - 1)); sbkt[p] = (unsigned short)b;
    }
    __syncthreads();
    // write-out: consecutive j in a bucket run -> consecutive dest (coalesced bursts)
    for (int j = t; j < CHUNK; j += 256) {
        int b = sbkt[j];
        if (b < NB)
            __builtin_nontemporal_store(sedge[j], bedges + s[b] + j);
    }
}

// ---- psort: pass-1 LDS degree hist (restored) + 8-padded runs + coalesced write ----
__global__ __launch_bounds__(256) void k_psort(
        const int* __restrict__ cursor, const int* __restrict__ bedges,
        int* __restrict__ bedges2, float* __restrict__ dinv,
        int* __restrict__ node_off, int* __restrict__ node_nq, int n) {
    __shared__ int cnt[BUCKET];
    __shared__ int sc[BUCKET];                 // padded inclusive scan
    __shared__ int cur[BUCKET];
    __shared__ int sedge[BSTR2];               // 34 KB ranked srcs
    int b = blockIdx.x, t = threadIdx.x;
    int base = b * BSTR;
    int ne = cursor[b] - base;
    if (t < BUCKET) cnt[t] = 0;
    __syncthreads();
    int nq = ne >> 2, tail = ne & 3;
    for (int q = t; q < nq; q += 256) {
        int4v v = *(const int4v*)(bedges + base + (q << 2));
        atomicAdd(&cnt[v.x & 127], 1);
        atomicAdd(&cnt[v.y & 127], 1);
        atomicAdd(&cnt[v.z & 127], 1);
        atomicAdd(&cnt[v.w & 127], 1);
    }
    if (t < tail) atomicAdd(&cnt[bedges[base + (nq << 2) + t] & 127], 1);
    __syncthreads();
    int p = 0;
    if (t < BUCKET) { p = (cnt[t] + 7) & ~7; sc[t] = p; }   // 8-edge pad -> agg ILP 8
    __syncthreads();
    for (int off = 1; off < BUCKET; off <<= 1) {
        int v = 0;
        if (t < BUCKET) { v = sc[t]; if (t >= off) v += sc[t - off]; }
        __syncthreads();
        if (t < BUCKET) sc[t] = v;
        __syncthreads();
    }
    if (t < BUCKET) {
        int w = sc[t] - p;
        cur[t] = w;
        int node = b * BUCKET + t;
        if (node < n) {
            dinv[node] = rsqrtf((float)(cnt[t] + 1));   // +1 self-loop
            node_off[node] = b * BSTR2 + w;
            node_nq[node] = p >> 3;                     // #8-edge groups
        }
    }
    __syncthreads();
    // pass 2: rank into LDS
    for (int q = t; q < nq; q += 256) {
        int4v v = *(const int4v*)(bedges + base + (q << 2));
        int pos;
        pos = atomicAdd(&cur[v.x & 127], 1); sedge[pos] = v.x >> 8;
        pos = atomicAdd(&cur[v.y & 127], 1); sedge[pos] = v.y >> 8;
        pos = atomicAdd(&cur[v.z & 127], 1); sedge[pos] = v.z >> 8;
        pos = atomicAdd(&cur[v.w & 127], 1); sedge[pos] = v.w >> 8;
    }
    if (t < tail) {
        int v = bedges[base + (nq << 2) + t];
        int pos = atomicAdd(&cur[v & 127], 1); sedge[pos] = v >> 8;
    }
    __syncthreads();
    if (t < BUCKET) {
        int endc = cur[t];
        for (int i = endc; i < sc[t]; ++i) sedge[i] = n;   // sentinel -> zero row
    }
    __syncthreads();
    int total = sc[BUCKET - 1];                // multiple of 8
    int* dst2 = bedges2 + b * BSTR2;           // 16B-aligned (BSTR2*4 % 16 == 0)
    for (int j4 = t; j4 < (total >> 2); j4 += 256) {
        int4v v = *(const int4v*)(sedge + (j4 << 2));
        __builtin_nontemporal_store(v, (int4v*)(dst2 + (j4 << 2)));
    }
}

// ---- GEMM1 (wave-split-K, FULL K=512): 8 lanes/row, writes bf16 h1b directly ----
__global__ __launch_bounds__(256) void k_gemm1wf(
        const float* __restrict__ x, const float* __restrict__ W,
        const float* __restrict__ dinv, unsigned int* __restrict__ h1u, int n) {
    __shared__ float2v Ws[512 * WSTR];         // 36864 B -> 4 blocks/CU
    int t = threadIdx.x;

    // stage full W: 4096 float2 -> Ws[k*WSTR + c2]
    const float2v* Wg = (const float2v*)W;
#pragma unroll
    for (int it = 0; it < 16; ++it) {
        int m = it * 256 + t;                  // m in [0,4096)
        Ws[(m >> 3) * WSTR + (m & 7)] = Wg[m];
    }
    __syncthreads();

    int r  = blockIdx.x * 32 + (t >> 3);       // 32 rows/block, 8 lanes/row
    int kl = t & 7;                            // K sub-lane
    if (r >= n) return;
    const float* xr = x + (size_t)r * F_IN + kl * 4;
    float4v v[16];
#pragma unroll
    for (int i = 0; i < 16; ++i)
        v[i] = *(const float4v*)(xr + i * 32);

    float2v acc2[8];
#pragma unroll
    for (int c2 = 0; c2 < 8; ++c2) acc2[c2] = (float2v){0.0f, 0.0f};

#pragma unroll
    for (int i = 0; i < 16; ++i) {
        int kb = i * 32 + kl * 4;
#pragma unroll
        for (int j = 0; j < 4; ++j) {
            float xv = v[i][j];
            const float2v* wr = Ws + (kb + j) * WSTR;
#pragma unroll
            for (int c2 = 0; c2 < 8; ++c2)
                acc2[c2] += xv * wr[c2];
        }
    }
    // reduce over the 8 K-lanes (xor masks 1,2,4 stay within the row group)
#pragma unroll
    for (int m = 1; m <= 4; m <<= 1) {
#pragma unroll
        for (int c2 = 0; c2 < 8; ++c2) {
            acc2[c2].x += __shfl_xor(acc2[c2].x, m);
            acc2[c2].y += __shfl_xor(acc2[c2].y, m);
        }
    }
    float dv = dinv[r];
    unsigned int u = (unsigned int)f2bf(dv * acc2[kl].x)
                   | ((unsigned int)f2bf(dv * acc2[kl].y) << 16);
    h1u[(size_t)r * 8 + kl] = u;               // lane kl owns cols {2kl, 2kl+1}
}

// ---- agg layer 1 + relu/bias + GEMM2 fused: 8 lanes/node, 2 quads/iter (ILP 8) ----
__global__ __launch_bounds__(1024) void k_aggF1(
        const int* __restrict__ node_off, const int* __restrict__ node_nq,
        const int* __restrict__ bedges2, const unsigned int* __restrict__ h1u,
        const float* __restrict__ dinv, const float* __restrict__ b1,
        const float* __restrict__ W2, unsigned short* __restrict__ h2b, int n) {
    int tg = blockIdx.x * 1024 + threadIdx.x;
    int node = tg >> 3, c = tg & 7;            // lane owns cols {2c, 2c+1}
    if (node >= n) return;
    int off = node_off[node], nq = node_nq[node];
    unsigned int su = h1u[(size_t)node * 8 + c];        // self-loop (pre-scaled)
    float ax = bf2f((unsigned short)su);
    float ay = bf2f((unsigned short)(su >> 16));
    for (int q = 0; q < nq; ++q) {             // nq = #8-edge groups
        const int4v* bp = (const int4v*)(bedges2 + off + (q << 3));
        int4v s0 = bp[0], s1 = bp[1];
        unsigned int u0 = h1u[(size_t)s0.x * 8 + c];
        unsigned int u1 = h1u[(size_t)s0.y * 8 + c];
        unsigned int u2 = h1u[(size_t)s0.z * 8 + c];
        unsigned int u3 = h1u[(size_t)s0.w * 8 + c];
        unsigned int u4 = h1u[(size_t)s1.x * 8 + c];
        unsigned int u5 = h1u[(size_t)s1.y * 8 + c];
        unsigned int u6 = h1u[(size_t)s1.z * 8 + c];
        unsigned int u7 = h1u[(size_t)s1.w * 8 + c];
        ax += bf2f((unsigned short)u0) + bf2f((unsigned short)u1)
            + bf2f((unsigned short)u2) + bf2f((unsigned short)u3)
            + bf2f((unsigned short)u4) + bf2f((unsigned short)u5)
            + bf2f((unsigned short)u6) + bf2f((unsigned short)u7);
        ay += bf2f((unsigned short)(u0 >> 16)) + bf2f((unsigned short)(u1 >> 16))
            + bf2f((unsigned short)(u2 >> 16)) + bf2f((unsigned short)(u3 >> 16))
            + bf2f((unsigned short)(u4 >> 16)) + bf2f((unsigned short)(u5 >> 16))
            + bf2f((unsigned short)(u6 >> 16)) + bf2f((unsigned short)(u7 >> 16));
    }
    float dv = dinv[node];
    float zx = fmaxf(dv * ax + b1[2 * c], 0.0f);
    float zy = fmaxf(dv * ay + b1[2 * c + 1], 0.0f);
    float h[F_OUT];
#pragma unroll
    for (int o = 0; o < F_OUT; ++o)
        h[o] = zx * W2[(2 * c) * F_OUT + o] + zy * W2[(2 * c + 1) * F_OUT + o];
#pragma unroll
    for (int sft = 4; sft >= 1; sft >>= 1)
#pragma unroll
        for (int o = 0; o < F_OUT; ++o) h[o] += __shfl_xor(h[o], sft, 8);
    unsigned short w = (c < F_OUT) ? f2bf(dv * h[c]) : (unsigned short)0;
    h2b[((size_t)node << 3) + c] = w;
}

// ------ agg layer 2 + bias fused: 4 lanes/node, 2 quads/iter (ILP 8) ------
__global__ __launch_bounds__(1024) void k_aggF2(
        const int* __restrict__ node_off, const int* __restrict__ node_nq,
        const int* __restrict__ bedges2, const unsigned int* __restrict__ h2u,
        const float* __restrict__ dinv, const float* __restrict__ b2,
        float* __restrict__ out, int n) {
    int tg = blockIdx.x * 1024 + threadIdx.x;
    int node = tg >> 2, c = tg & 3;            // lane owns cols {2c, 2c+1}
    if (node >= n) return;
    int off = node_off[node], nq = node_nq[node];
    unsigned int su = h2u[(size_t)node * 4 + c];        // self-loop (col7 = 0)
    float ax = bf2f((unsigned short)su);
    float ay = bf2f((unsigned short)(su >> 16));
    for (int q = 0; q < nq; ++q) {             // nq = #8-edge groups
        const int4v* bp = (const int4v*)(bedges2 + off + (q << 3));
        int4v s0 = bp[0], s1 = bp[1];
        unsigned int u0 = h2u[(size_t)s0.x * 4 + c];
        unsigned int u1 = h2u[(size_t)s0.y * 4 + c];
        unsigned int u2 = h2u[(size_t)s0.z * 4 + c];
        unsigned int u3 = h2u[(size_t)s0.w * 4 + c];
        unsigned int u4 = h2u[(size_t)s1.x * 4 + c];
        unsigned int u5 = h2u[(size_t)s1.y * 4 + c];
        unsigned int u6 = h2u[(size_t)s1.z * 4 + c];
        unsigned int u7 = h2u[(size_t)s1.w * 4 + c];
        ax += bf2f((unsigned short)u0) + bf2f((unsigned short)u1)
            + bf2f((unsigned short)u2) + bf2f((unsigned short)u3)
            + bf2f((unsigned short)u4) + bf2f((unsigned short)u5)
            + bf2f((unsigned short)u6) + bf2f((unsigned short)u7);
        ay += bf2f((unsigned short)(u0 >> 16)) + bf2f((unsigned short)(u1 >> 16))
            + bf2f((unsigned short)(u2 >> 16)) + bf2f((unsigned short)(u3 >> 16))
            + bf2f((unsigned short)(u4 >> 16)) + bf2f((unsigned short)(u5 >> 16))
            + bf2f((unsigned short)(u6 >> 16)) + bf2f((unsigned short)(u7 >> 16));
    }
    float dv = dinv[node];
    out[(size_t)node * F_OUT + 2 * c] = dv * ax + b2[2 * c];
    if (2 * c + 1 < F_OUT)
        out[(size_t)node * F_OUT + 2 * c + 1] = dv * ay + b2[2 * c + 1];
}

extern "C" void kernel_launch(void* const* d_in, const int* in_sizes, int n_in,
                              void* d_out, int out_size, void* d_ws, size_t ws_size,
                              hipStream_t stream) {
    const float* x  = (const float*)d_in[0];
    const int*   ei = (const int*)d_in[1];      // int64 in source but JAX x64 off -> int32
    const float* W1 = (const float*)d_in[2];
    const float* b1 = (const float*)d_in[3];
    const float* W2 = (const float*)d_in[4];
    const float* b2 = (const float*)d_in[5];
    float* out = (float*)d_out;

    const int n = in_sizes[0] / F_IN;       // 100000
    const int E = in_sizes[1] / 2;          // 3200000
    const int* src = ei;
    const int* dst = ei + E;

    const int NB = (n + BUCKET - 1) / BUCKET;   // 782 (sentinel bucket NB fits < MAXNB)
    const int PBLK = (E + CHUNK - 1) / CHUNK;   // 782
    const int NRB = (n + 31) / 32;              // 3125 row-blocks for gemm1wf

    // workspace layout (16B-aligned sections)
    size_t Np = ((size_t)n + 3) & ~(size_t)3;
    char* ws = (char*)d_ws;
    int*   cursor       = (int*)ws;             ws += MAXNB * 4;
    float* dinv         = (float*)ws;           ws += Np * 4;
    int*   node_off     = (int*)ws;             ws += Np * 4;
    int*   node_nq      = (int*)ws;             ws += Np * 4;
    int*   bedges       = (int*)ws;             ws += (size_t)NB * BSTR * 4;    // 25.6 MB
    int*   bedges2      = (int*)ws;             ws += (size_t)NB * BSTR2 * 4;   // 27.2 MB
    unsigned short* h1b = (unsigned short*)ws;  ws += (Np + 4) * F_HID * 2;     // 3.2 MB
    unsigned short* h2b = (unsigned short*)ws;  ws += (Np + 4) * 8 * 2;         // 1.6 MB
    unsigned int* h1u = (unsigned int*)h1b;
    unsigned int* h2u = (unsigned int*)h2b;

    k_init    <<<(NB + 255) / 256, 256, 0, stream>>>(cursor, h1u, h2u, NB, n);
    k_place4  <<<PBLK, 256, 0, stream>>>(src, dst, cursor, bedges, E, NB);
    k_psort   <<<NB, 256, 0, stream>>>(cursor, bedges, bedges2, dinv, node_off, node_nq, n);
    k_gemm1wf <<<NRB, 256, 0, stream>>>(x, W1, dinv, h1u, n);
    k_aggF1   <<<((size_t)n * 8 + 1023) / 1024, 1024, 0, stream>>>(node_off, node_nq, bedges2, h1u, dinv, b1, W2, h2b, n);
    k_aggF2   <<<((size_t)n * 4 + 1023) / 1024, 1024, 0, stream>>>(node_off, node_nq, bedges2, h2u, dinv, b2, out, n);
}

// Round 16
// 389.270 us; speedup vs baseline: 1.4145x; 1.0802x over previous
//
#include <hip/hip_runtime.h>

#define F_IN 512
#define F_HID 16
#define F_OUT 7
#define BUCKET 128          // nodes per bucket
#define LB 7                // log2(BUCKET)
#define CHUNK 8192          // edges per partition block (391 blocks, 2/CU all-resident)
#define MAXNB 1024          // max buckets supported by block-local scans
#define BSTR 8192           // bedges fixed bucket stride (mean 4092, sigma 64 -> 64-sigma safe)
#define BSTR2 8704          // bedges2 fixed stride (8-pad worst case ~5300 < 8704)

// GEMM1 (wave-split-K, full K): 8 lanes per row, W in LDS
#define WSTR 9              // LDS W row stride in float2 (9 -> 8 kl-lanes hit 8 bank-pairs)

typedef int   int4v   __attribute__((ext_vector_type(4)));
typedef float float2v __attribute__((ext_vector_type(2)));
typedef float float4v __attribute__((ext_vector_type(4)));
typedef unsigned int uint4v __attribute__((ext_vector_type(4)));

static __device__ __forceinline__ unsigned short f2bf(float f) {   // RNE
    unsigned int u = __float_as_uint(f);
    u += 0x7FFFu + ((u >> 16) & 1u);
    return (unsigned short)(u >> 16);
}
static __device__ __forceinline__ float bf2f(unsigned short s) {
    return __uint_as_float((unsigned int)s << 16);
}

// ---- init: fixed-stride bucket cursors + zero sentinel rows of h1b/h2b ----
__global__ void k_init(int* __restrict__ cursor, unsigned int* __restrict__ h1u,
                       unsigned int* __restrict__ h2u, int NB, int n) {
    int i = blockIdx.x * 256 + threadIdx.x;
    if (i < NB) cursor[i] = i * BSTR;
    if (blockIdx.x == 0) {
        if (threadIdx.x < 8) h1u[(size_t)n * 8 + threadIdx.x] = 0u;
        if (threadIdx.x < 4) h2u[(size_t)n * 4 + threadIdx.x] = 0u;
    }
}

// ------- place: block rank-and-reorder, 512 thr x 8192 edges (halved scan instances) -------
// Stores are NOT nontemporal: bedges is re-read twice by psort (L3-warm handoff).
__global__ __launch_bounds__(512) void k_place4(
        const int* __restrict__ src, const int* __restrict__ dst,
        int* __restrict__ cursor, int* __restrict__ bedges, int E, int NB) {
    __shared__ int h[MAXNB];                   // hist -> exclusive rank cursor (4 KB)
    __shared__ int s[MAXNB];                   // inclusive scan -> dbase (4 KB)
    __shared__ int sedge[CHUNK];               // 32 KB reordered packed edges
    __shared__ unsigned short sbkt[CHUNK];     // 16 KB bucket id per slot
    int t = threadIdx.x, blk = blockIdx.x;
    for (int i = t; i < MAXNB; i += 512) h[i] = 0;
    __syncthreads();
    int base = blk * CHUNK;
    int4v d4[4], s4[4];
#pragma unroll
    for (int it = 0; it < 4; ++it) {
        int e = base + (it * 512 + t) * 4;
        if (e < E) {                           // E % 4 == 0 -> whole quad valid
            d4[it] = __builtin_nontemporal_load((const int4v*)(dst + e));
            s4[it] = __builtin_nontemporal_load((const int4v*)(src + e));
        } else {
            int sent = NB << LB;               // sentinel bucket NB (skipped at write-out)
            d4[it].x = sent; d4[it].y = sent; d4[it].z = sent; d4[it].w = sent;
            s4[it].x = 0;    s4[it].y = 0;    s4[it].z = 0;    s4[it].w = 0;
        }
        atomicAdd(&h[d4[it].x >> LB], 1);
        atomicAdd(&h[d4[it].y >> LB], 1);
        atomicAdd(&h[d4[it].z >> LB], 1);
        atomicAdd(&h[d4[it].w >> LB], 1);
    }
    __syncthreads();
    for (int i = t; i < MAXNB; i += 512) s[i] = h[i];
    __syncthreads();
    // inclusive Hillis-Steele scan of s[0..1023], 512 threads x 2
    for (int off = 1; off < MAXNB; off <<= 1) {
        int i1 = t, i2 = t + 512;
        int v1 = s[i1] + ((i1 >= off) ? s[i1 - off] : 0);
        int v2 = s[i2] + ((i2 >= off) ? s[i2 - off] : 0);
        __syncthreads();
        s[i1] = v1; s[i2] = v2;
        __syncthreads();
    }
    // h := exclusive rank base; s := dbase = (atomic run reservation) - local_excl
    for (int i = t; i < MAXNB; i += 512) {
        int incl = s[i], cnt = h[i];
        int excl = incl - cnt;
        h[i] = excl;
        int db = 0;
        if (i < NB && cnt > 0)
            db = atomicAdd(&cursor[i], cnt) - excl;    // device-scope global atomic
        s[i] = db;
    }
    __syncthreads();
    // rank & reorder into LDS
#pragma unroll
    for (int it = 0; it < 4; ++it) {
        int d, sv, b, p;
        d = d4[it].x; sv = s4[it].x; b = d >> LB; p = atomicAdd(&h[b], 1);
        sedge[p] = (sv << 8) | (d & (BUCKET - 1)); sbkt[p] = (unsigned short)b;
        d = d4[it].y; sv = s4[it].y; b = d >> LB; p = atomicAdd(&h[b], 1);
        sedge[p] = (sv << 8) | (d & (BUCKET - 1)); sbkt[p] = (unsigned short)b;
        d = d4[it].z; sv = s4[it].z; b = d >> LB; p = atomicAdd(&h[b], 1);
        sedge[p] = (sv << 8) | (d & (BUCKET - 1)); sbkt[p] = (unsigned short)b;
        d = d4[it].w; sv = s4[it].w; b = d >> LB; p = atomicAdd(&h[b], 1);
        sedge[p] = (sv << 8) | (d & (BUCKET - 1)); sbkt[p] = (unsigned short)b;
    }
    __syncthreads();
    // write-out: consecutive j in a bucket run -> consecutive dest (coalesced bursts)
    for (int j = t; j < CHUNK; j += 512) {
        int b = sbkt[j];
        if (b < NB)
            bedges[s[b] + j] = sedge[j];
    }
}

// ---- psort: pass-1 LDS degree hist + 8-padded runs + coalesced write (no nt) ----
__global__ __launch_bounds__(256) void k_psort(
        const int* __restrict__ cursor, const int* __restrict__ bedges,
        int* __restrict__ bedges2, float* __restrict__ dinv,
        int* __restrict__ node_off, int* __restrict__ node_nq, int n) {
    __shared__ int cnt[BUCKET];
    __shared__ int sc[BUCKET];                 // padded inclusive scan
    __shared__ int cur[BUCKET];
    __shared__ int sedge[BSTR2];               // 34 KB ranked srcs
    int b = blockIdx.x, t = threadIdx.x;
    int base = b * BSTR;
    int ne = cursor[b] - base;
    if (t < BUCKET) cnt[t] = 0;
    __syncthreads();
    int nq = ne >> 2, tail = ne & 3;
    for (int q = t; q < nq; q += 256) {
        int4v v = *(const int4v*)(bedges + base + (q << 2));
        atomicAdd(&cnt[v.x & 127], 1);
        atomicAdd(&cnt[v.y & 127], 1);
        atomicAdd(&cnt[v.z & 127], 1);
        atomicAdd(&cnt[v.w & 127], 1);
    }
    if (t < tail) atomicAdd(&cnt[bedges[base + (nq << 2) + t] & 127], 1);
    __syncthreads();
    int p = 0;
    if (t < BUCKET) { p = (cnt[t] + 7) & ~7; sc[t] = p; }   // 8-edge pad -> agg ILP 8
    __syncthreads();
    for (int off = 1; off < BUCKET; off <<= 1) {
        int v = 0;
        if (t < BUCKET) { v = sc[t]; if (t >= off) v += sc[t - off]; }
        __syncthreads();
        if (t < BUCKET) sc[t] = v;
        __syncthreads();
    }
    if (t < BUCKET) {
        int w = sc[t] - p;
        cur[t] = w;
        int node = b * BUCKET + t;
        if (node < n) {
            dinv[node] = rsqrtf((float)(cnt[t] + 1));   // +1 self-loop
            node_off[node] = b * BSTR2 + w;
            node_nq[node] = p >> 3;                     // #8-edge groups
        }
    }
    __syncthreads();
    // pass 2: rank into LDS
    for (int q = t; q < nq; q += 256) {
        int4v v = *(const int4v*)(bedges + base + (q << 2));
        int pos;
        pos = atomicAdd(&cur[v.x & 127], 1); sedge[pos] = v.x >> 8;
        pos = atomicAdd(&cur[v.y & 127], 1); sedge[pos] = v.y >> 8;
        pos = atomicAdd(&cur[v.z & 127], 1); sedge[pos] = v.z >> 8;
        pos = atomicAdd(&cur[v.w & 127], 1); sedge[pos] = v.w >> 8;
    }
    if (t < tail) {
        int v = bedges[base + (nq << 2) + t];
        int pos = atomicAdd(&cur[v & 127], 1); sedge[pos] = v >> 8;
    }
    __syncthreads();
    if (t < BUCKET) {
        int endc = cur[t];
        for (int i = endc; i < sc[t]; ++i) sedge[i] = n;   // sentinel -> zero row
    }
    __syncthreads();
    int total = sc[BUCKET - 1];                // multiple of 8
    int* dst2 = bedges2 + b * BSTR2;           // 16B-aligned (BSTR2*4 % 16 == 0)
    for (int j4 = t; j4 < (total >> 2); j4 += 256) {
        int4v v = *(const int4v*)(sedge + (j4 << 2));
        *(int4v*)(dst2 + (j4 << 2)) = v;       // no nt: aggF1/aggF2 re-read this
    }
}

// ---- GEMM1 (wave-split-K, FULL K=512): 8 lanes/row, writes bf16 h1b directly ----
__global__ __launch_bounds__(256) void k_gemm1wf(
        const float* __restrict__ x, const float* __restrict__ W,
        const float* __restrict__ dinv, unsigned int* __restrict__ h1u, int n) {
    __shared__ float2v Ws[512 * WSTR];         // 36864 B -> 4 blocks/CU
    int t = threadIdx.x;

    // stage full W: 4096 float2 -> Ws[k*WSTR + c2]
    const float2v* Wg = (const float2v*)W;
#pragma unroll
    for (int it = 0; it < 16; ++it) {
        int m = it * 256 + t;                  // m in [0,4096)
        Ws[(m >> 3) * WSTR + (m & 7)] = Wg[m];
    }
    __syncthreads();

    int r  = blockIdx.x * 32 + (t >> 3);       // 32 rows/block, 8 lanes/row
    int kl = t & 7;                            // K sub-lane
    if (r >= n) return;
    const float* xr = x + (size_t)r * F_IN + kl * 4;
    float4v v[16];
#pragma unroll
    for (int i = 0; i < 16; ++i)
        v[i] = *(const float4v*)(xr + i * 32);

    float2v acc2[8];
#pragma unroll
    for (int c2 = 0; c2 < 8; ++c2) acc2[c2] = (float2v){0.0f, 0.0f};

#pragma unroll
    for (int i = 0; i < 16; ++i) {
        int kb = i * 32 + kl * 4;
#pragma unroll
        for (int j = 0; j < 4; ++j) {
            float xv = v[i][j];
            const float2v* wr = Ws + (kb + j) * WSTR;
#pragma unroll
            for (int c2 = 0; c2 < 8; ++c2)
                acc2[c2] += xv * wr[c2];
        }
    }
    // reduce over the 8 K-lanes (xor masks 1,2,4 stay within the row group)
#pragma unroll
    for (int m = 1; m <= 4; m <<= 1) {
#pragma unroll
        for (int c2 = 0; c2 < 8; ++c2) {
            acc2[c2].x += __shfl_xor(acc2[c2].x, m);
            acc2[c2].y += __shfl_xor(acc2[c2].y, m);
        }
    }
    float dv = dinv[r];
    unsigned int u = (unsigned int)f2bf(dv * acc2[kl].x)
                   | ((unsigned int)f2bf(dv * acc2[kl].y) << 16);
    h1u[(size_t)r * 8 + kl] = u;               // lane kl owns cols {2kl, 2kl+1}
}

// ---- agg layer 1 + relu/bias + GEMM2 fused: 8 lanes/node, 2 quads/iter (ILP 8) ----
__global__ __launch_bounds__(1024) void k_aggF1(
        const int* __restrict__ node_off, const int* __restrict__ node_nq,
        const int* __restrict__ bedges2, const unsigned int* __restrict__ h1u,
        const float* __restrict__ dinv, const float* __restrict__ b1,
        const float* __restrict__ W2, unsigned short* __restrict__ h2b, int n) {
    int tg = blockIdx.x * 1024 + threadIdx.x;
    int node = tg >> 3, c = tg & 7;            // lane owns cols {2c, 2c+1}
    if (node >= n) return;
    int off = node_off[node], nq = node_nq[node];
    unsigned int su = h1u[(size_t)node * 8 + c];        // self-loop (pre-scaled)
    float ax = bf2f((unsigned short)su);
    float ay = bf2f((unsigned short)(su >> 16));
    for (int q = 0; q < nq; ++q) {             // nq = #8-edge groups
        const int4v* bp = (const int4v*)(bedges2 + off + (q << 3));
        int4v s0 = bp[0], s1 = bp[1];
        unsigned int u0 = h1u[(size_t)s0.x * 8 + c];
        unsigned int u1 = h1u[(size_t)s0.y * 8 + c];
        unsigned int u2 = h1u[(size_t)s0.z * 8 + c];
        unsigned int u3 = h1u[(size_t)s0.w * 8 + c];
        unsigned int u4 = h1u[(size_t)s1.x * 8 + c];
        unsigned int u5 = h1u[(size_t)s1.y * 8 + c];
        unsigned int u6 = h1u[(size_t)s1.z * 8 + c];
        unsigned int u7 = h1u[(size_t)s1.w * 8 + c];
        ax += bf2f((unsigned short)u0) + bf2f((unsigned short)u1)
            + bf2f((unsigned short)u2) + bf2f((unsigned short)u3)
            + bf2f((unsigned short)u4) + bf2f((unsigned short)u5)
            + bf2f((unsigned short)u6) + bf2f((unsigned short)u7);
        ay += bf2f((unsigned short)(u0 >> 16)) + bf2f((unsigned short)(u1 >> 16))
            + bf2f((unsigned short)(u2 >> 16)) + bf2f((unsigned short)(u3 >> 16))
            + bf2f((unsigned short)(u4 >> 16)) + bf2f((unsigned short)(u5 >> 16))
            + bf2f((unsigned short)(u6 >> 16)) + bf2f((unsigned short)(u7 >> 16));
    }
    float dv = dinv[node];
    float zx = fmaxf(dv * ax + b1[2 * c], 0.0f);
    float zy = fmaxf(dv * ay + b1[2 * c + 1], 0.0f);
    float h[F_OUT];
#pragma unroll
    for (int o = 0; o < F_OUT; ++o)
        h[o] = zx * W2[(2 * c) * F_OUT + o] + zy * W2[(2 * c + 1) * F_OUT + o];
#pragma unroll
    for (int sft = 4; sft >= 1; sft >>= 1)
#pragma unroll
        for (int o = 0; o < F_OUT; ++o) h[o] += __shfl_xor(h[o], sft, 8);
    unsigned short w = (c < F_OUT) ? f2bf(dv * h[c]) : (unsigned short)0;
    h2b[((size_t)node << 3) + c] = w;
}

// ------ agg layer 2 + bias fused: 4 lanes/node, 2 quads/iter (ILP 8) ------
__global__ __launch_bounds__(1024) void k_aggF2(
        const int* __restrict__ node_off, const int* __restrict__ node_nq,
        const int* __restrict__ bedges2, const unsigned int* __restrict__ h2u,
        const float* __restrict__ dinv, const float* __restrict__ b2,
        float* __restrict__ out, int n) {
    int tg = blockIdx.x * 1024 + threadIdx.x;
    int node = tg >> 2, c = tg & 3;            // lane owns cols {2c, 2c+1}
    if (node >= n) return;
    int off = node_off[node], nq = node_nq[node];
    unsigned int su = h2u[(size_t)node * 4 + c];        // self-loop (col7 = 0)
    float ax = bf2f((unsigned short)su);
    float ay = bf2f((unsigned short)(su >> 16));
    for (int q = 0; q < nq; ++q) {             // nq = #8-edge groups
        const int4v* bp = (const int4v*)(bedges2 + off + (q << 3));
        int4v s0 = bp[0], s1 = bp[1];
        unsigned int u0 = h2u[(size_t)s0.x * 4 + c];
        unsigned int u1 = h2u[(size_t)s0.y * 4 + c];
        unsigned int u2 = h2u[(size_t)s0.z * 4 + c];
        unsigned int u3 = h2u[(size_t)s0.w * 4 + c];
        unsigned int u4 = h2u[(size_t)s1.x * 4 + c];
        unsigned int u5 = h2u[(size_t)s1.y * 4 + c];
        unsigned int u6 = h2u[(size_t)s1.z * 4 + c];
        unsigned int u7 = h2u[(size_t)s1.w * 4 + c];
        ax += bf2f((unsigned short)u0) + bf2f((unsigned short)u1)
            + bf2f((unsigned short)u2) + bf2f((unsigned short)u3)
            + bf2f((unsigned short)u4) + bf2f((unsigned short)u5)
            + bf2f((unsigned short)u6) + bf2f((unsigned short)u7);
        ay += bf2f((unsigned short)(u0 >> 16)) + bf2f((unsigned short)(u1 >> 16))
            + bf2f((unsigned short)(u2 >> 16)) + bf2f((unsigned short)(u3 >> 16))
            + bf2f((unsigned short)(u4 >> 16)) + bf2f((unsigned short)(u5 >> 16))
            + bf2f((unsigned short)(u6 >> 16)) + bf2f((unsigned short)(u7 >> 16));
    }
    float dv = dinv[node];
    out[(size_t)node * F_OUT + 2 * c] = dv * ax + b2[2 * c];
    if (2 * c + 1 < F_OUT)
        out[(size_t)node * F_OUT + 2 * c + 1] = dv * ay + b2[2 * c + 1];
}

extern "C" void kernel_launch(void* const* d_in, const int* in_sizes, int n_in,
                              void* d_out, int out_size, void* d_ws, size_t ws_size,
                              hipStream_t stream) {
    const float* x  = (const float*)d_in[0];
    const int*   ei = (const int*)d_in[1];      // int64 in source but JAX x64 off -> int32
    const float* W1 = (const float*)d_in[2];
    const float* b1 = (const float*)d_in[3];
    const float* W2 = (const float*)d_in[4];
    const float* b2 = (const float*)d_in[5];
    float* out = (float*)d_out;

    const int n = in_sizes[0] / F_IN;       // 100000
    const int E = in_sizes[1] / 2;          // 3200000
    const int* src = ei;
    const int* dst = ei + E;

    const int NB = (n + BUCKET - 1) / BUCKET;   // 782 (sentinel bucket NB fits < MAXNB)
    const int PBLK = (E + CHUNK - 1) / CHUNK;   // 391
    const int NRB = (n + 31) / 32;              // 3125 row-blocks for gemm1wf

    // workspace layout (16B-aligned sections)
    size_t Np = ((size_t)n + 3) & ~(size_t)3;
    char* ws = (char*)d_ws;
    int*   cursor       = (int*)ws;             ws += MAXNB * 4;
    float* dinv         = (float*)ws;           ws += Np * 4;
    int*   node_off     = (int*)ws;             ws += Np * 4;
    int*   node_nq      = (int*)ws;             ws += Np * 4;
    int*   bedges       = (int*)ws;             ws += (size_t)NB * BSTR * 4;    // 25.6 MB
    int*   bedges2      = (int*)ws;             ws += (size_t)NB * BSTR2 * 4;   // 27.2 MB
    unsigned short* h1b = (unsigned short*)ws;  ws += (Np + 4) * F_HID * 2;     // 3.2 MB
    unsigned short* h2b = (unsigned short*)ws;  ws += (Np + 4) * 8 * 2;         // 1.6 MB
    unsigned int* h1u = (unsigned int*)h1b;
    unsigned int* h2u = (unsigned int*)h2b;

    k_init    <<<(NB + 255) / 256, 256, 0, stream>>>(cursor, h1u, h2u, NB, n);
    k_place4  <<<PBLK, 512, 0, stream>>>(src, dst, cursor, bedges, E, NB);
    k_psort   <<<NB, 256, 0, stream>>>(cursor, bedges, bedges2, dinv, node_off, node_nq, n);
    k_gemm1wf <<<NRB, 256, 0, stream>>>(x, W1, dinv, h1u, n);
    k_aggF1   <<<((size_t)n * 8 + 1023) / 1024, 1024, 0, stream>>>(node_off, node_nq, bedges2, h1u, dinv, b1, W2, h2b, n);
    k_aggF2   <<<((size_t)n * 4 + 1023) / 1024, 1024, 0, stream>>>(node_off, node_nq, bedges2, h2u, dinv, b2, out, n);
}